// Round 10
// baseline (301.603 us; speedup 1.0000x reference)
//
#include <hip/hip_runtime.h>
#include <hip/hip_bf16.h>
#include <stdint.h>

typedef unsigned short ushort_t;
typedef __attribute__((ext_vector_type(8))) short short8;
typedef __attribute__((ext_vector_type(4))) float floatx4;

#define DEV __device__ __forceinline__

DEV ushort_t f2b(float f) {
  uint32_t x = __float_as_uint(f);
  uint32_t r = (x + 0x7FFFu + ((x >> 16) & 1u)) >> 16;
  return (ushort_t)r;
}
DEV float b2f(ushort_t u) { return __uint_as_float(((uint32_t)u) << 16); }

DEV void async16(const ushort_t* g, ushort_t* l) {
  __builtin_amdgcn_global_load_lds(
      (const __attribute__((address_space(1))) void*)g,
      (__attribute__((address_space(3))) void*)l, 16, 0, 0);
}

// ---------------- fused fp32 -> bf16 conversion (one launch) ----------------
struct Cvt7 {
  const float* src[7];
  ushort_t* dst[7];
  float scale[7];
  unsigned start[8];  // prefix, in float4 units
};
__global__ void cvt_all(Cvt7 a) {
  unsigned idx = blockIdx.x * blockDim.x + threadIdx.x;
  if (idx >= a.start[7]) return;
  int seg = 0;
#pragma unroll
  for (int j = 1; j < 7; j++) seg += (idx >= a.start[j]) ? 1 : 0;
  unsigned off = idx - a.start[seg];
  float sc = a.scale[seg];
  float4 v = ((const float4*)a.src[seg])[off];
  ((ushort4*)a.dst[seg])[off] =
      make_ushort4(f2b(v.x * sc), f2b(v.y * sc), f2b(v.z * sc), f2b(v.w * sc));
}

// ---------------- bf16 GEMM: C[M,N] = A[M,K=ldk] * B[N,ldk]^T ---------------
// Tile = (32*MT) x 128, 256 thr (4 waves 2x2), wave tile (16*MT) x 64.
// BK=64, 2-barrier K-loop (R5: dbuf regressed). Staging bound = MT (R6 bug).
// XOR LDS swizzle: 0 bank conflicts (R2-R9).
// R9 finding: time tracks per-block MFMA count x block count, NOT barrier
// count / FETCH / epilogue (MODE2-MT4 == MODE3-MT2 at 512 MFMA/block, 1024
// blocks, ~690 TF, MfmaUtil ~27%). -> MT=2 everywhere K=1024: half the
// per-block work, double the blocks (6 blocks/CU resident at 24KB LDS).
// XCD mapping (XCD = HW-flat-id % 8):
//  SWZ=0 natural: XCD = x%8 -> bx-colocation (B slice/XCD must fit L2).
//  SWZ=1 y-coloc: all bx of one A row-group on one XCD (full B must fit L2).
//  SWZ=2 cluster2 (gx=8, gy=64): 2 bx x 32 by per XCD.
// MODE 0: outB = bf16(acc)                         (QKV)
// MODE 1: outB = bf16(acc); outF = acc + bias      (mid; WOb pre-scaled x2)
// MODE 2: outB = bf16(relu(acc + bias[n]))         (MLP hidden)
// MODE 3: outF[z*M*N+idx] = acc                    (split-K partials)
template <int MODE, int MT, int SWZ>
__launch_bounds__(256)
__global__ void gemm_bt(const ushort_t* __restrict__ A, const ushort_t* __restrict__ Bm,
                        int M, int N, int Kd, int ldk,
                        ushort_t* __restrict__ outB, float* __restrict__ outF,
                        const float* __restrict__ bias) {
  constexpr int TM = 32 * MT;
  __shared__ alignas(16) ushort_t As[TM * 64];
  __shared__ alignas(16) ushort_t Bs[128 * 64];
  const int tid = threadIdx.x;
  const int wave = tid >> 6, lane = tid & 63;
  const int wm = wave >> 1, wn = wave & 1;

  int bx, by;
  if constexpr (SWZ == 1) {
    const int f = blockIdx.x + gridDim.x * blockIdx.y;
    by = (f & 7) + 8 * (f / (8 * gridDim.x));
    bx = (f >> 3) % gridDim.x;
  } else if constexpr (SWZ == 2) {
    const int x = blockIdx.x, y = blockIdx.y;  // gx=8: XCD = x
    bx = 2 * (x & 3) + (y & 1);
    by = (y >> 1) + 32 * (x >> 2);
  } else {
    bx = blockIdx.x; by = blockIdx.y;
  }
  const int m0 = by * TM, n0 = bx * 128;
  const int kz = blockIdx.z * Kd;

  floatx4 acc[MT][4];
#pragma unroll
  for (int i = 0; i < MT; i++)
#pragma unroll
    for (int j = 0; j < 4; j++) acc[i][j] = (floatx4){0.f, 0.f, 0.f, 0.f};

  // staging: 16B/lane; call j covers 8 rows; global k-chunk (lane&7)^((lane>>3)&7)
  const int r8 = lane >> 3;
  const int scol = (((lane & 7) ^ (r8 & 7)) * 8);
  const ushort_t* gA = A + (size_t)(m0 + wave * (TM / 4) + r8) * ldk + kz + scol;
  const ushort_t* gB = Bm + (size_t)(n0 + wave * 32 + r8) * ldk + kz + scol;
  ushort_t* lA = As + wave * (TM / 4) * 64;
  ushort_t* lB = Bs + wave * 2048;

  const int fr = lane & 15, fq = lane >> 4;
  const int sw = fr & 7;
  const ushort_t* rdA = As + (wm * 16 * MT + fr) * 64;
  const ushort_t* rdB = Bs + (wn * 64 + fr) * 64;

  for (int k0 = 0; k0 < Kd; k0 += 64) {
#pragma unroll
    for (int j = 0; j < MT; j++) async16(gA + (size_t)j * 8 * ldk, lA + j * 512);
#pragma unroll
    for (int j = 0; j < 4; j++) async16(gB + (size_t)j * 8 * ldk, lB + j * 512);
    gA += 64; gB += 64;
    __syncthreads();
#pragma unroll
    for (int h = 0; h < 2; h++) {
      const int co = ((h * 4 + fq) ^ sw) * 8;
      short8 af[MT], bfv[4];
#pragma unroll
      for (int mt = 0; mt < MT; mt++) af[mt] = *(const short8*)(rdA + mt * 16 * 64 + co);
#pragma unroll
      for (int nt = 0; nt < 4; nt++) bfv[nt] = *(const short8*)(rdB + nt * 16 * 64 + co);
#pragma unroll
      for (int mt = 0; mt < MT; mt++)
#pragma unroll
        for (int nt = 0; nt < 4; nt++)
          acc[mt][nt] = __builtin_amdgcn_mfma_f32_16x16x32_bf16(af[mt], bfv[nt], acc[mt][nt], 0, 0, 0);
    }
    __syncthreads();
  }

  const int crow = m0 + wm * 16 * MT + (lane >> 4) * 4;
  const int ccol = n0 + wn * 64 + (lane & 15);
  const size_t zoff = (size_t)blockIdx.z * M * N;
#pragma unroll
  for (int mt = 0; mt < MT; mt++)
#pragma unroll
    for (int nt = 0; nt < 4; nt++) {
      floatx4 a = acc[mt][nt];
#pragma unroll
      for (int r = 0; r < 4; r++) {
        const int gm = crow + mt * 16 + r;
        const int gn = ccol + nt * 16;
        const size_t idx = (size_t)gm * N + gn;
        float v = a[r];
        if constexpr (MODE == 0) {
          outB[idx] = f2b(v);
        } else if constexpr (MODE == 1) {
          outB[idx] = f2b(v);          // WOb pre-scaled by 2 in cvt
          outF[idx] = v + bias[gn];
        } else if constexpr (MODE == 2) {
          float t = v + bias[gn];
          outB[idx] = f2b(t > 0.f ? t : 0.f);
        } else {
          outF[zoff + idx] = v;
        }
      }
    }
}

// ---------------- split-K=2 reduction: out += P0 + P1 -----------------------
__launch_bounds__(256)
__global__ void reduce2(const float4* __restrict__ P, float4* __restrict__ out, int n4) {
  int i = blockIdx.x * blockDim.x + threadIdx.x;
  int st = gridDim.x * blockDim.x;
  for (; i < n4; i += st) {
    float4 a = out[i];
    float4 p0 = P[i], p1 = P[i + 1048576];
    a.x += p0.x + p1.x;
    a.y += p0.y + p1.y;
    a.z += p0.z + p1.z;
    a.w += p0.w + p1.w;
    out[i] = a;
  }
}

// ---------------- attention (degenerate mask -> diag + suffix sum) ----------
// z[q] = (e_q*v[q] + sum_{p>q} v[p]) / (e_q + (S-1-q)), e_q = exp(q.k/8)
__launch_bounds__(256)
__global__ void attn1(const ushort_t* __restrict__ qkv,
                      float* __restrict__ eG, float* __restrict__ psumG) {
  const int c = blockIdx.x & 31;
  const int i = (blockIdx.x >> 5) & 15;
  const int b = blockIdx.x >> 9;
  const int t = threadIdx.x, wave = t >> 6, h = t & 63;
  const size_t rowbase = (size_t)b * 2048 * 3072;
  float vacc = 0.f;
#pragma unroll 4
  for (int r = 0; r < 16; r++) {
    const int s = c * 64 + wave * 16 + r;
    const size_t rb = rowbase + (size_t)s * 3072 + i * 64 + h;
    float q = b2f(qkv[rb]);
    float k = b2f(qkv[rb + 1024]);
    float v = b2f(qkv[rb + 2048]);
    float d = q * k;
#pragma unroll
    for (int off = 32; off > 0; off >>= 1) d += __shfl_xor(d, off, 64);
    if (h == 0) eG[((size_t)(b * 16 + i)) * 2048 + s] = __expf(d * 0.125f);
    vacc += v;
  }
  __shared__ float vs[4][64];
  vs[wave][h] = vacc;
  __syncthreads();
  if (t < 64)
    psumG[(((size_t)(b * 16 + i)) * 32 + c) * 64 + t] =
        vs[0][t] + vs[1][t] + vs[2][t] + vs[3][t];
}

// Pass 2: 256 blocks x 256 thr; each wave owns one 64-s chunk. Loads batched
// 16-deep (independent of the serial `run` chain) for latency hiding.
__launch_bounds__(256)
__global__ void attn2(const ushort_t* __restrict__ qkv,
                      const float* __restrict__ eG, const float* __restrict__ psumG,
                      ushort_t* __restrict__ Z) {
  const int wave = threadIdx.x >> 6, h = threadIdx.x & 63;
  const int c = (blockIdx.x & 7) * 4 + wave;
  const int i = (blockIdx.x >> 3) & 15;
  const int b = blockIdx.x >> 7;
  const size_t rowbase = (size_t)b * 2048 * 3072;
  const size_t pbase = ((size_t)(b * 16 + i)) * 32;
  float run = 0.f;
#pragma unroll 8
  for (int cc = c + 1; cc < 32; cc++) run += psumG[(pbase + cc) * 64 + h];
  const size_t ebase = ((size_t)(b * 16 + i)) * 2048;
  for (int t4 = 3; t4 >= 0; t4--) {
    float vv[16], ee[16];
#pragma unroll
    for (int j = 0; j < 16; j++) {
      const int s = c * 64 + t4 * 16 + j;
      vv[j] = b2f(qkv[rowbase + (size_t)s * 3072 + 2048 + i * 64 + h]);
      ee[j] = eG[ebase + s];
    }
#pragma unroll
    for (int j = 15; j >= 0; j--) {
      const int s = c * 64 + t4 * 16 + j;
      float z = (ee[j] * vv[j] + run) / (ee[j] + (float)(2047 - s));
      Z[((size_t)b * 2048 + s) * 1024 + i * 64 + h] = f2b(z);
      run += vv[j];
    }
  }
}

// ---------------- launch ----------------------------------------------------
extern "C" void kernel_launch(void* const* d_in, const int* in_sizes, int n_in,
                              void* d_out, int out_size, void* d_ws, size_t ws_size,
                              hipStream_t stream) {
  const float* x     = (const float*)d_in[0];
  const float* W_Q   = (const float*)d_in[1];
  const float* W_K   = (const float*)d_in[2];
  const float* W_V   = (const float*)d_in[3];
  const float* W_O   = (const float*)d_in[4];
  const float* W_in  = (const float*)d_in[5];
  const float* b_in  = (const float*)d_in[6];
  const float* W_out = (const float*)d_in[7];
  const float* b_out = (const float*)d_in[8];
  float* out = (float*)d_out;

  // ws layout. P (32 MB split-K partials) aliases [0,32): Xb/Wqkv/WOb/Z dead
  // by MODE3 (Z consumed by MODE1, QKV by attn2, midb/Winb by MODE2).
  char* base = (char*)d_ws;
  const size_t MB = 1048576;
  ushort_t* Xb    = (ushort_t*)(base + 0 * MB);    // 8 MB
  ushort_t* Wqkv  = (ushort_t*)(base + 8 * MB);    // 6 MB
  ushort_t* WOb   = (ushort_t*)(base + 14 * MB);   // 2 MB
  ushort_t* Z     = (ushort_t*)(base + 16 * MB);   // 8 MB
  ushort_t* QKV   = (ushort_t*)(base + 24 * MB);   // 24 MB
  ushort_t* midb  = (ushort_t*)(base + 48 * MB);   // 8 MB
  ushort_t* Winb  = (ushort_t*)(base + 56 * MB);   // 8 MB
  ushort_t* Woutb = (ushort_t*)(base + 64 * MB);   // 8 MB
  ushort_t* Hb    = (ushort_t*)(base + 72 * MB);   // 32 MB
  float*    P     = (float*)(base + 0 * MB);       // 32 MB [0,32) alias
  float*    eG    = (float*)(base + 104 * MB);           // 256 KB
  float*    psumG = (float*)(base + 104 * MB + 262144);  // 256 KB

  Cvt7 ca;
  ca.src[0] = x;     ca.dst[0] = Xb;               ca.scale[0] = 1.f;
  ca.src[1] = W_Q;   ca.dst[1] = Wqkv;             ca.scale[1] = 1.f;
  ca.src[2] = W_K;   ca.dst[2] = Wqkv + 1048576;   ca.scale[2] = 1.f;
  ca.src[3] = W_V;   ca.dst[3] = Wqkv + 2097152;   ca.scale[3] = 1.f;
  ca.src[4] = W_O;   ca.dst[4] = WOb;              ca.scale[4] = 2.f;  // fold mid=2*attn_out
  ca.src[5] = W_in;  ca.dst[5] = Winb;             ca.scale[5] = 1.f;
  ca.src[6] = W_out; ca.dst[6] = Woutb;            ca.scale[6] = 1.f;
  unsigned n4s[7] = {1048576, 262144, 262144, 262144, 262144, 1048576, 1048576};
  unsigned acc4 = 0;
  for (int j = 0; j < 7; j++) { ca.start[j] = acc4; acc4 += n4s[j]; }
  ca.start[7] = acc4;
  cvt_all<<<dim3((acc4 + 255) / 256), dim3(256), 0, stream>>>(ca);

  // QKV = X * Wqkv^T [4096,3072]. MT=2: 1536 blocks, 6/CU. Natural map:
  // XCD = x%8 -> 3 B-slices (768 KB) L2-resident; A streams via L3.
  gemm_bt<0, 2, 0><<<dim3(24, 64), 256, 0, stream>>>(Xb, Wqkv, 4096, 3072, 1024, 1024,
                                                     QKV, nullptr, nullptr);
  // attention -> Z [4096, 1024] bf16
  attn1<<<dim3(1024), 256, 0, stream>>>(QKV, eG, psumG);
  attn2<<<dim3(256), 256, 0, stream>>>(QKV, eG, psumG, Z);
  // mid = Z*(2*W_O)^T: y-coloc (full B = 2 MB fits L2; A fetched once)
  gemm_bt<1, 2, 1><<<dim3(8, 64), 256, 0, stream>>>(Z, WOb, 4096, 1024, 1024, 1024,
                                                    midb, out, b_out);
  // H = relu(mid*W_in^T + b_in) [4096,4096]. MT=2: 2048 blocks, 6/CU.
  // Natural: 4 B-slices = 1 MB/XCD L2-resident.
  gemm_bt<2, 2, 0><<<dim3(32, 64), 256, 0, stream>>>(midb, Winb, 4096, 4096, 1024, 1024,
                                                     Hb, nullptr, b_in);
  // P[z] = H slice * W_out^T. cluster2: 2 bx x 32 by per XCD.
  gemm_bt<3, 2, 2><<<dim3(8, 64, 2), 256, 0, stream>>>(Hb, Woutb, 4096, 1024, 2048, 4096,
                                                       nullptr, P, nullptr);
  // out += P0 + P1
  reduce2<<<dim3(1024), 256, 0, stream>>>((const float4*)P, (float4*)out, 1048576);
}

// Round 11
// 282.613 us; speedup vs baseline: 1.0672x; 1.0672x over previous
//
#include <hip/hip_runtime.h>
#include <hip/hip_bf16.h>
#include <stdint.h>

typedef unsigned short ushort_t;
typedef __attribute__((ext_vector_type(8))) short short8;
typedef __attribute__((ext_vector_type(4))) float floatx4;

#define DEV __device__ __forceinline__

DEV ushort_t f2b(float f) {
  uint32_t x = __float_as_uint(f);
  uint32_t r = (x + 0x7FFFu + ((x >> 16) & 1u)) >> 16;
  return (ushort_t)r;
}
DEV float b2f(ushort_t u) { return __uint_as_float(((uint32_t)u) << 16); }

DEV void async16(const ushort_t* g, ushort_t* l) {
  __builtin_amdgcn_global_load_lds(
      (const __attribute__((address_space(1))) void*)g,
      (__attribute__((address_space(3))) void*)l, 16, 0, 0);
}

// ---------------- fused fp32 -> bf16 conversion (one launch) ----------------
struct Cvt7 {
  const float* src[7];
  ushort_t* dst[7];
  float scale[7];
  unsigned start[8];  // prefix, in float4 units
};
__global__ void cvt_all(Cvt7 a) {
  unsigned idx = blockIdx.x * blockDim.x + threadIdx.x;
  if (idx >= a.start[7]) return;
  int seg = 0;
#pragma unroll
  for (int j = 1; j < 7; j++) seg += (idx >= a.start[j]) ? 1 : 0;
  unsigned off = idx - a.start[seg];
  float sc = a.scale[seg];
  float4 v = ((const float4*)a.src[seg])[off];
  ((ushort4*)a.dst[seg])[off] =
      make_ushort4(f2b(v.x * sc), f2b(v.y * sc), f2b(v.z * sc), f2b(v.w * sc));
}

// ---------------- bf16 GEMM: C[M,N] = A[M,K=ldk] * B[N,ldk]^T ---------------
// Tile = (32*MT) x 128, 256 thr (4 waves 2x2), wave tile (16*MT) x 64.
// BK=64, 2-barrier K-loop (R5: dbuf regressed). Staging bound = MT (R6 bug).
// XOR LDS swizzle: 0 bank conflicts (R2-R10).
// R10 finding (falsifies R9 theory): MT=2 on the big GEMMs REGRESSED — the
// plateau tracks aggregate staged bytes (MT=2 doubles B restaging), not
// block count. MT=4 for MODE0/2; MT=2 only where grid would be 256.
// XCD mapping (XCD = HW-flat-id % 8):
//  SWZ=0 natural: XCD = x%8 (B slice/XCD must fit L2).
//  SWZ=1 y-coloc: all bx of one A row-group on one XCD (full B must fit L2).
//  SWZ=2 cluster2 (gx=8, gy=64): 2 bx x 32 by per XCD.
// MODE 0: outB = bf16(acc)                         (QKV)
// MODE 1: outB = bf16(acc); outF = acc + bias      (mid; WOb pre-scaled x2)
// MODE 2: outB = bf16(relu(acc + bias[n]))         (MLP hidden)
// MODE 3: outF[z*M*N+idx] = acc                    (split-K partials)
template <int MODE, int MT, int SWZ>
__launch_bounds__(256)
__global__ void gemm_bt(const ushort_t* __restrict__ A, const ushort_t* __restrict__ Bm,
                        int M, int N, int Kd, int ldk,
                        ushort_t* __restrict__ outB, float* __restrict__ outF,
                        const float* __restrict__ bias) {
  constexpr int TM = 32 * MT;
  __shared__ alignas(16) ushort_t As[TM * 64];
  __shared__ alignas(16) ushort_t Bs[128 * 64];
  const int tid = threadIdx.x;
  const int wave = tid >> 6, lane = tid & 63;
  const int wm = wave >> 1, wn = wave & 1;

  int bx, by;
  if constexpr (SWZ == 1) {
    const int f = blockIdx.x + gridDim.x * blockIdx.y;
    by = (f & 7) + 8 * (f / (8 * gridDim.x));
    bx = (f >> 3) % gridDim.x;
  } else if constexpr (SWZ == 2) {
    const int x = blockIdx.x, y = blockIdx.y;  // gx=8: XCD = x
    bx = 2 * (x & 3) + (y & 1);
    by = (y >> 1) + 32 * (x >> 2);
  } else {
    bx = blockIdx.x; by = blockIdx.y;
  }
  const int m0 = by * TM, n0 = bx * 128;
  const int kz = blockIdx.z * Kd;

  floatx4 acc[MT][4];
#pragma unroll
  for (int i = 0; i < MT; i++)
#pragma unroll
    for (int j = 0; j < 4; j++) acc[i][j] = (floatx4){0.f, 0.f, 0.f, 0.f};

  // staging: 16B/lane; call j covers 8 rows; global k-chunk (lane&7)^((lane>>3)&7)
  const int r8 = lane >> 3;
  const int scol = (((lane & 7) ^ (r8 & 7)) * 8);
  const ushort_t* gA = A + (size_t)(m0 + wave * (TM / 4) + r8) * ldk + kz + scol;
  const ushort_t* gB = Bm + (size_t)(n0 + wave * 32 + r8) * ldk + kz + scol;
  ushort_t* lA = As + wave * (TM / 4) * 64;
  ushort_t* lB = Bs + wave * 2048;

  const int fr = lane & 15, fq = lane >> 4;
  const int sw = fr & 7;
  const ushort_t* rdA = As + (wm * 16 * MT + fr) * 64;
  const ushort_t* rdB = Bs + (wn * 64 + fr) * 64;

  for (int k0 = 0; k0 < Kd; k0 += 64) {
#pragma unroll
    for (int j = 0; j < MT; j++) async16(gA + (size_t)j * 8 * ldk, lA + j * 512);
#pragma unroll
    for (int j = 0; j < 4; j++) async16(gB + (size_t)j * 8 * ldk, lB + j * 512);
    gA += 64; gB += 64;
    __syncthreads();
#pragma unroll
    for (int h = 0; h < 2; h++) {
      const int co = ((h * 4 + fq) ^ sw) * 8;
      short8 af[MT], bfv[4];
#pragma unroll
      for (int mt = 0; mt < MT; mt++) af[mt] = *(const short8*)(rdA + mt * 16 * 64 + co);
#pragma unroll
      for (int nt = 0; nt < 4; nt++) bfv[nt] = *(const short8*)(rdB + nt * 16 * 64 + co);
#pragma unroll
      for (int mt = 0; mt < MT; mt++)
#pragma unroll
        for (int nt = 0; nt < 4; nt++)
          acc[mt][nt] = __builtin_amdgcn_mfma_f32_16x16x32_bf16(af[mt], bfv[nt], acc[mt][nt], 0, 0, 0);
    }
    __syncthreads();
  }

  const int crow = m0 + wm * 16 * MT + (lane >> 4) * 4;
  const int ccol = n0 + wn * 64 + (lane & 15);
  const size_t zoff = (size_t)blockIdx.z * M * N;
#pragma unroll
  for (int mt = 0; mt < MT; mt++)
#pragma unroll
    for (int nt = 0; nt < 4; nt++) {
      floatx4 a = acc[mt][nt];
#pragma unroll
      for (int r = 0; r < 4; r++) {
        const int gm = crow + mt * 16 + r;
        const int gn = ccol + nt * 16;
        const size_t idx = (size_t)gm * N + gn;
        float v = a[r];
        if constexpr (MODE == 0) {
          outB[idx] = f2b(v);
        } else if constexpr (MODE == 1) {
          outB[idx] = f2b(v);          // WOb pre-scaled by 2 in cvt
          outF[idx] = v + bias[gn];
        } else if constexpr (MODE == 2) {
          float t = v + bias[gn];
          outB[idx] = f2b(t > 0.f ? t : 0.f);
        } else {
          outF[zoff + idx] = v;
        }
      }
    }
}

// ---------------- split-K=2 reduction: out += P0 + P1 -----------------------
__launch_bounds__(256)
__global__ void reduce2(const float4* __restrict__ P, float4* __restrict__ out, int n4) {
  int i = blockIdx.x * blockDim.x + threadIdx.x;
  int st = gridDim.x * blockDim.x;
  for (; i < n4; i += st) {
    float4 a = out[i];
    float4 p0 = P[i], p1 = P[i + 1048576];
    a.x += p0.x + p1.x;
    a.y += p0.y + p1.y;
    a.z += p0.z + p1.z;
    a.w += p0.w + p1.w;
    out[i] = a;
  }
}

// ---------------- attention (degenerate mask -> diag + suffix sum) ----------
// z[q] = (e_q*v[q] + sum_{p>q} v[p]) / (e_q + (S-1-q)), e_q = exp(q.k/8)
// Pass 1: 32-s chunks. grid = 2*16*64 = 2048 blocks x 256 thr; wave covers
// 8 s (r<8). Writes eG[s] and psumG[chunk][h].
__launch_bounds__(256)
__global__ void attn1(const ushort_t* __restrict__ qkv,
                      float* __restrict__ eG, float* __restrict__ psumG) {
  const int c = blockIdx.x & 63;
  const int i = (blockIdx.x >> 6) & 15;
  const int b = blockIdx.x >> 10;
  const int t = threadIdx.x, wave = t >> 6, h = t & 63;
  const size_t rowbase = (size_t)b * 2048 * 3072;
  float vacc = 0.f;
#pragma unroll
  for (int r = 0; r < 8; r++) {
    const int s = c * 32 + wave * 8 + r;
    const size_t rb = rowbase + (size_t)s * 3072 + i * 64 + h;
    float q = b2f(qkv[rb]);
    float k = b2f(qkv[rb + 1024]);
    float v = b2f(qkv[rb + 2048]);
    float d = q * k;
#pragma unroll
    for (int off = 32; off > 0; off >>= 1) d += __shfl_xor(d, off, 64);
    if (h == 0) eG[((size_t)(b * 16 + i)) * 2048 + s] = __expf(d * 0.125f);
    vacc += v;
  }
  __shared__ float vs[4][64];
  vs[wave][h] = vacc;
  __syncthreads();
  if (t < 64)
    psumG[(((size_t)(b * 16 + i)) * 64 + c) * 64 + t] =
        vs[0][t] + vs[1][t] + vs[2][t] + vs[3][t];
}

// Pass 2: 512 blocks x 256 thr (2 blocks/CU); each wave owns one 32-s chunk.
// Suffix over later psums, then backward walk (loads batched 16-deep).
__launch_bounds__(256)
__global__ void attn2(const ushort_t* __restrict__ qkv,
                      const float* __restrict__ eG, const float* __restrict__ psumG,
                      ushort_t* __restrict__ Z) {
  const int wave = threadIdx.x >> 6, h = threadIdx.x & 63;
  const int c = (blockIdx.x & 15) * 4 + wave;
  const int i = (blockIdx.x >> 4) & 15;
  const int b = blockIdx.x >> 8;
  const size_t rowbase = (size_t)b * 2048 * 3072;
  const size_t pbase = ((size_t)(b * 16 + i)) * 64;
  float run = 0.f;
#pragma unroll 8
  for (int cc = c + 1; cc < 64; cc++) run += psumG[(pbase + cc) * 64 + h];
  const size_t ebase = ((size_t)(b * 16 + i)) * 2048;
  for (int t4 = 1; t4 >= 0; t4--) {
    float vv[16], ee[16];
#pragma unroll
    for (int j = 0; j < 16; j++) {
      const int s = c * 32 + t4 * 16 + j;
      vv[j] = b2f(qkv[rowbase + (size_t)s * 3072 + 2048 + i * 64 + h]);
      ee[j] = eG[ebase + s];
    }
#pragma unroll
    for (int j = 15; j >= 0; j--) {
      const int s = c * 32 + t4 * 16 + j;
      float z = (ee[j] * vv[j] + run) / (ee[j] + (float)(2047 - s));
      Z[((size_t)b * 2048 + s) * 1024 + i * 64 + h] = f2b(z);
      run += vv[j];
    }
  }
}

// ---------------- launch ----------------------------------------------------
extern "C" void kernel_launch(void* const* d_in, const int* in_sizes, int n_in,
                              void* d_out, int out_size, void* d_ws, size_t ws_size,
                              hipStream_t stream) {
  const float* x     = (const float*)d_in[0];
  const float* W_Q   = (const float*)d_in[1];
  const float* W_K   = (const float*)d_in[2];
  const float* W_V   = (const float*)d_in[3];
  const float* W_O   = (const float*)d_in[4];
  const float* W_in  = (const float*)d_in[5];
  const float* b_in  = (const float*)d_in[6];
  const float* W_out = (const float*)d_in[7];
  const float* b_out = (const float*)d_in[8];
  float* out = (float*)d_out;

  // ws layout (max 104 MB).
  // P (32 MB) aliases [0,32): Xb/Wqkv/WOb/Z dead by MODE3.
  // eG/psumG live inside Hb's region [72,104): consumed by attn2 BEFORE
  // MODE2 writes Hb (stream-ordered), so no conflict.
  char* base = (char*)d_ws;
  const size_t MB = 1048576;
  ushort_t* Xb    = (ushort_t*)(base + 0 * MB);    // 8 MB
  ushort_t* Wqkv  = (ushort_t*)(base + 8 * MB);    // 6 MB
  ushort_t* WOb   = (ushort_t*)(base + 14 * MB);   // 2 MB
  ushort_t* Z     = (ushort_t*)(base + 16 * MB);   // 8 MB
  ushort_t* QKV   = (ushort_t*)(base + 24 * MB);   // 24 MB
  ushort_t* midb  = (ushort_t*)(base + 48 * MB);   // 8 MB
  ushort_t* Winb  = (ushort_t*)(base + 56 * MB);   // 8 MB
  ushort_t* Woutb = (ushort_t*)(base + 64 * MB);   // 8 MB
  ushort_t* Hb    = (ushort_t*)(base + 72 * MB);   // 32 MB
  float*    P     = (float*)(base + 0 * MB);       // 32 MB [0,32) alias
  float*    psumG = (float*)(base + 72 * MB);            // 512 KB (pre-MODE2)
  float*    eG    = (float*)(base + 72 * MB + 524288);   // 256 KB (pre-MODE2)

  Cvt7 ca;
  ca.src[0] = x;     ca.dst[0] = Xb;               ca.scale[0] = 1.f;
  ca.src[1] = W_Q;   ca.dst[1] = Wqkv;             ca.scale[1] = 1.f;
  ca.src[2] = W_K;   ca.dst[2] = Wqkv + 1048576;   ca.scale[2] = 1.f;
  ca.src[3] = W_V;   ca.dst[3] = Wqkv + 2097152;   ca.scale[3] = 1.f;
  ca.src[4] = W_O;   ca.dst[4] = WOb;              ca.scale[4] = 2.f;  // fold mid=2*attn_out
  ca.src[5] = W_in;  ca.dst[5] = Winb;             ca.scale[5] = 1.f;
  ca.src[6] = W_out; ca.dst[6] = Woutb;            ca.scale[6] = 1.f;
  unsigned n4s[7] = {1048576, 262144, 262144, 262144, 262144, 1048576, 1048576};
  unsigned acc4 = 0;
  for (int j = 0; j < 7; j++) { ca.start[j] = acc4; acc4 += n4s[j]; }
  ca.start[7] = acc4;
  cvt_all<<<dim3((acc4 + 255) / 256), dim3(256), 0, stream>>>(ca);

  // QKV = X * Wqkv^T [4096,3072]. MT=4 (R9 proven): 768 blocks, natural map
  // (3 B-slices = 768 KB L2-resident per XCD; A streams via L3).
  gemm_bt<0, 4, 0><<<dim3(24, 32), 256, 0, stream>>>(Xb, Wqkv, 4096, 3072, 1024, 1024,
                                                     QKV, nullptr, nullptr);
  // attention -> Z [4096, 1024] bf16 (32-s chunks; attn2 at 2 blocks/CU)
  attn1<<<dim3(2048), 256, 0, stream>>>(QKV, eG, psumG);
  attn2<<<dim3(512), 256, 0, stream>>>(QKV, eG, psumG, Z);
  // mid = Z*(2*W_O)^T: y-coloc (full B = 2 MB fits L2; A fetched once)
  gemm_bt<1, 2, 1><<<dim3(8, 64), 256, 0, stream>>>(Z, WOb, 4096, 1024, 1024, 1024,
                                                    midb, out, b_out);
  // H = relu(mid*W_in^T + b_in) [4096,4096]. MT=4 (R9 proven): 1024 blocks,
  // natural map (4 B-slices = 1 MB/XCD L2-resident).
  gemm_bt<2, 4, 0><<<dim3(32, 32), 256, 0, stream>>>(midb, Winb, 4096, 4096, 1024, 1024,
                                                     Hb, nullptr, b_in);
  // P[z] = H slice * W_out^T. cluster2: 2 bx x 32 by per XCD.
  gemm_bt<3, 2, 2><<<dim3(8, 64, 2), 256, 0, stream>>>(Hb, Woutb, 4096, 1024, 2048, 4096,
                                                       nullptr, P, nullptr);
  // out += P0 + P1
  reduce2<<<dim3(1024), 256, 0, stream>>>((const float4*)P, (float4*)out, 1048576);
}